// Round 10
// baseline (218.071 us; speedup 1.0000x reference)
//
#include <hip/hip_runtime.h>

// F0=64, F1=128, F2=64. n<=65536, buckets of 128 nodes, slotted CSR with
// fixed bucket capacity CAP (no hist/scan passes).
// Pipeline: memset(cnt) -> place_direct -> prep(srcdeg+scale+bucketsort) ->
//           gather24(xb->agg1b bf16) -> gemm12 (fused both layers, H in LDS)
//           -> gather24(y2b->out f32,+b2)

#define NBMAX 512
#define CAPLOG 12
#define CAP (1 << CAPLOG)

__device__ inline unsigned short f2bf(float f) {
    unsigned int u = __float_as_uint(f);
    unsigned int r = (u + 0x7FFFu + ((u >> 16) & 1u)) >> 16;  // RNE
    return (unsigned short)r;
}
__device__ inline float bf2f_lo(unsigned int u) { return __uint_as_float(u << 16); }
__device__ inline float bf2f_hi(unsigned int u) { return __uint_as_float(u & 0xFFFF0000u); }
__device__ inline float bf2f(unsigned short h) {
    return __uint_as_float((unsigned int)h << 16);
}

// One pass over edges: per-block LDS hist -> one global reservation atomic per
// (block,bucket) -> LDS-cursor scatter into slotted bucket arrays.
// src entry: 1B local id. dst entry: (dst&127)<<25 | src.
__global__ __launch_bounds__(256) void place_direct(const int* __restrict__ src,
        const int* __restrict__ dst, int* __restrict__ cnt_s, int* __restrict__ cnt_d,
        unsigned char* __restrict__ ss, unsigned int* __restrict__ sd,
        int n_edges, int nb) {
    __shared__ int hs[NBMAX], hd[NBMAX], bs[NBMAX], bd[NBMAX];
    for (int i = threadIdx.x; i < nb; i += 256) { hs[i] = 0; hd[i] = 0; }
    __syncthreads();
    int chunk = (n_edges + gridDim.x - 1) / gridDim.x;
    int e0 = blockIdx.x * chunk;
    int e1 = e0 + chunk; if (e1 > n_edges) e1 = n_edges;
    for (int e = e0 + (int)threadIdx.x; e < e1; e += 256) {
        atomicAdd(&hs[src[e] >> 7], 1);
        atomicAdd(&hd[dst[e] >> 7], 1);
    }
    __syncthreads();
    for (int i = threadIdx.x; i < nb; i += 256) {
        int v = hs[i]; bs[i] = v ? atomicAdd(&cnt_s[i], v) : 0; hs[i] = 0;
        v = hd[i];     bd[i] = v ? atomicAdd(&cnt_d[i], v) : 0; hd[i] = 0;
    }
    __syncthreads();
    for (int e = e0 + (int)threadIdx.x; e < e1; e += 256) {
        int s = src[e], d = dst[e];
        int sb = s >> 7, db = d >> 7;
        int ps = bs[sb] + atomicAdd(&hs[sb], 1);
        ss[((size_t)sb << CAPLOG) + ps] = (unsigned char)(s & 127);
        int pd = bd[db] + atomicAdd(&hd[db], 1);
        sd[((size_t)db << CAPLOG) + pd] = ((unsigned int)(d & 127) << 25) | (unsigned int)s;
    }
}

// One block per bucket b:
//  phase 1 (src side): count ss local ids -> norm_src; xb = bf16(h * norm).
//  phase 2 (dst side): 128-bin count of sd -> scan -> node_rng + counting-sorted
//                      srt (u16 src ids) + norm_dst.
__global__ __launch_bounds__(256) void prep(const float* __restrict__ h,
        const unsigned char* __restrict__ ss, const int* __restrict__ cnt_s,
        const unsigned int* __restrict__ sd, const int* __restrict__ cnt_d,
        float* __restrict__ norm_src, unsigned short* __restrict__ xb,
        int2* __restrict__ node_rng, unsigned short* __restrict__ srt,
        float* __restrict__ norm_dst, int n) {
    __shared__ int cnt[128], cur[128];
    __shared__ float nrm[128];
    __shared__ int w0tot;
    const int b = blockIdx.x;
    const int tid = threadIdx.x;

    // ---- phase 1: src degree + scale/cast ----
    if (tid < 128) cnt[tid] = 0;
    __syncthreads();
    {
        int used = cnt_s[b];
        const unsigned char* p = ss + ((size_t)b << CAPLOG);
        for (int i = tid; i < used; i += 256) atomicAdd(&cnt[p[i]], 1);
    }
    __syncthreads();
    if (tid < 128) {
        int c = cnt[tid]; if (c < 1) c = 1;
        float s = 1.0f / sqrtf((float)c);
        nrm[tid] = s;
        int node = (b << 7) + tid;
        if (node < n) norm_src[node] = s;
    }
    __syncthreads();
    {
        int base = b << 7;
        for (int t = tid; t < 128 * 16; t += 256) {
            int r = t >> 4, c4 = (t & 15) << 2;
            int node = base + r;
            if (node < n) {
                float s = nrm[r];
                float4 v = *(const float4*)(h + (size_t)node * 64 + c4);
                ushort4 o;
                o.x = f2bf(v.x * s); o.y = f2bf(v.y * s);
                o.z = f2bf(v.z * s); o.w = f2bf(v.w * s);
                *(ushort4*)(xb + (size_t)node * 64 + c4) = o;
            }
        }
    }
    __syncthreads();

    // ---- phase 2: dst bucket counting sort ----
    if (tid < 128) cnt[tid] = 0;
    __syncthreads();
    int used = cnt_d[b];
    const unsigned int* p = sd + ((size_t)b << CAPLOG);
    for (int i = tid; i < used; i += 256) atomicAdd(&cnt[p[i] >> 25], 1);
    __syncthreads();
    int lane = tid & 63, wid = tid >> 6;
    int v = (tid < 128) ? cnt[tid] : 0;
    int incl = v;
    #pragma unroll
    for (int d = 1; d < 64; d <<= 1) {
        int t = __shfl_up(incl, d, 64);
        if (lane >= d) incl += t;
    }
    if (tid == 63) w0tot = incl;
    __syncthreads();
    if (tid < 128) {
        int excl = incl - v + (wid == 1 ? w0tot : 0);
        cur[tid] = excl;
        int node = (b << 7) + tid;
        if (node < n) {
            int base = b << CAPLOG;
            node_rng[node] = make_int2(base + excl, base + excl + v);
            int c = v; if (c < 1) c = 1;
            norm_dst[node] = 1.0f / sqrtf((float)c);
        }
    }
    __syncthreads();
    for (int i = tid; i < used; i += 256) {
        unsigned int e = p[i];
        int l = (int)(e >> 25);
        int pos = atomicAdd(&cur[l], 1);
        srt[((size_t)b << CAPLOG) + pos] = (unsigned short)(e & 0xFFFFu);
    }
}

// One wave per dst node. 8 lanes x bf16x8 (16B dwordx4) cover the 64-wide row;
// 8 lane-groups x unroll 3 -> 24 edges in flight per round.
// f32 accumulate, 3-level shfl_xor reduce; writes bf16 row (mode 1) or f32
// row +bias (mode 0).
__global__ __launch_bounds__(256) void gather24(const unsigned short* __restrict__ xb,
        const unsigned short* __restrict__ srt, const int2* __restrict__ node_rng,
        const float* __restrict__ nrm, const float* __restrict__ bias,
        void* __restrict__ outp, int write_bf, int n_nodes) {
    int node = blockIdx.x * 4 + (threadIdx.x >> 6);
    if (node >= n_nodes) return;
    int lane = threadIdx.x & 63;
    int g  = lane >> 3;         // edge slot 0..7
    int c8 = (lane & 7) * 8;    // column base
    int2 rng = node_rng[node];
    int a0 = rng.x, a1 = rng.y;
    float acc[8];
    #pragma unroll
    for (int j = 0; j < 8; ++j) acc[j] = 0.f;
    for (int base = a0; base < a1; base += 24) {
        #pragma unroll
        for (int u = 0; u < 3; ++u) {
            int ei = base + u * 8 + g;
            int idx = ei < a1 ? ei : a1 - 1;
            float msk = ei < a1 ? 1.0f : 0.0f;
            int s = srt[idx];
            const uint4 v = *(const uint4*)(xb + (size_t)s * 64 + c8);
            acc[0] = fmaf(bf2f_lo(v.x), msk, acc[0]);
            acc[1] = fmaf(bf2f_hi(v.x), msk, acc[1]);
            acc[2] = fmaf(bf2f_lo(v.y), msk, acc[2]);
            acc[3] = fmaf(bf2f_hi(v.y), msk, acc[3]);
            acc[4] = fmaf(bf2f_lo(v.z), msk, acc[4]);
            acc[5] = fmaf(bf2f_hi(v.z), msk, acc[5]);
            acc[6] = fmaf(bf2f_lo(v.w), msk, acc[6]);
            acc[7] = fmaf(bf2f_hi(v.w), msk, acc[7]);
        }
    }
    #pragma unroll
    for (int off = 8; off < 64; off <<= 1) {
        #pragma unroll
        for (int j = 0; j < 8; ++j) acc[j] += __shfl_xor(acc[j], off, 64);
    }
    if (g == 0) {
        float s = nrm[node];
        float r[8];
        #pragma unroll
        for (int j = 0; j < 8; ++j) r[j] = acc[j] * s;
        if (write_bf) {
            unsigned short rb[8];
            #pragma unroll
            for (int j = 0; j < 8; ++j) rb[j] = f2bf(r[j]);
            unsigned short* o = (unsigned short*)outp + (size_t)node * 64 + c8;
            *(ushort4*)(o)     = make_ushort4(rb[0], rb[1], rb[2], rb[3]);
            *(ushort4*)(o + 4) = make_ushort4(rb[4], rb[5], rb[6], rb[7]);
        } else {
            if (bias) {
                #pragma unroll
                for (int j = 0; j < 8; ++j) r[j] += bias[c8 + j];
            }
            float* o = (float*)outp + (size_t)node * 64 + c8;
            *(float4*)(o)     = make_float4(r[0], r[1], r[2], r[3]);
            *(float4*)(o + 4) = make_float4(r[4], r[5], r[6], r[7]);
        }
    }
}

// Fused both layers per 64-node tile:
//   H = bf16(relu(Ab@W1 + b1) * norm_src)   (H kept in LDS only)
//   y2b = bf16(H @ W2)
// LDS: W1b 16K + W2b 16K + As(stride 74) 9.5K + Hs(stride 138) 17.7K + b1s.
__global__ __launch_bounds__(256) void gemm12(const unsigned short* __restrict__ Ab,
        const float* __restrict__ W1, const float* __restrict__ b1,
        const float* __restrict__ norm, const float* __restrict__ W2,
        unsigned short* __restrict__ y2b, int n_nodes) {
    __shared__ unsigned short W1b[64 * 128];   // [k][j]
    __shared__ unsigned short W2b[128 * 64];   // [k][j]
    __shared__ unsigned short As[64 * 74];     // [m][k] padded
    __shared__ unsigned short Hs[64 * 138];    // [m][k] padded
    __shared__ float b1s[128];
    const int tid = threadIdx.x;
    for (int i = tid; i < 8192; i += 256) W1b[i] = f2bf(W1[i]);
    for (int i = tid; i < 8192; i += 256) W2b[i] = f2bf(W2[i]);
    if (tid < 128) b1s[tid] = b1[tid];

    const int m0 = blockIdx.x * 64;
    const ushort4* Ag = (const ushort4*)(Ab + (size_t)m0 * 64);
    for (int i = tid; i < 1024; i += 256) {   // 64 rows x 16 ushort4
        int m = i >> 4, k4 = (i & 15) << 2;
        ushort4 u = make_ushort4(0, 0, 0, 0);
        if (m0 + m < n_nodes) u = Ag[i];
        *(ushort4*)(As + m * 74 + k4) = u;
    }
    __syncthreads();

    const int tx = tid & 15;   // cols tx*8..+7 (layer1) / tx*4..+3 (layer2)
    const int ty = tid >> 4;   // nodes ty*4..+3

    // ---- layer 1 ----
    float acc[4][8];
    #pragma unroll
    for (int i = 0; i < 4; ++i)
        #pragma unroll
        for (int j = 0; j < 8; ++j) acc[i][j] = 0.f;
    {
        const unsigned short* Ap = As + ty * 4 * 74;
        const unsigned short* Wp = W1b + tx * 8;
        for (int k = 0; k < 64; k += 4) {
            uint2 ar[4];
            #pragma unroll
            for (int i = 0; i < 4; ++i) ar[i] = *(const uint2*)(Ap + i * 74 + k);
            #pragma unroll
            for (int kk = 0; kk < 4; ++kk) {
                const uint4 wv = *(const uint4*)(Wp + (k + kk) * 128);
                float w0 = bf2f_lo(wv.x), w1 = bf2f_hi(wv.x);
                float w2 = bf2f_lo(wv.y), w3 = bf2f_hi(wv.y);
                float w4 = bf2f_lo(wv.z), w5 = bf2f_hi(wv.z);
                float w6 = bf2f_lo(wv.w), w7 = bf2f_hi(wv.w);
                #pragma unroll
                for (int i = 0; i < 4; ++i) {
                    unsigned int half = (kk < 2) ? ar[i].x : ar[i].y;
                    float a = (kk & 1) ? bf2f_hi(half) : bf2f_lo(half);
                    acc[i][0] = fmaf(a, w0, acc[i][0]);
                    acc[i][1] = fmaf(a, w1, acc[i][1]);
                    acc[i][2] = fmaf(a, w2, acc[i][2]);
                    acc[i][3] = fmaf(a, w3, acc[i][3]);
                    acc[i][4] = fmaf(a, w4, acc[i][4]);
                    acc[i][5] = fmaf(a, w5, acc[i][5]);
                    acc[i][6] = fmaf(a, w6, acc[i][6]);
                    acc[i][7] = fmaf(a, w7, acc[i][7]);
                }
            }
        }
    }
    // epilogue layer 1 -> Hs (bf16)
    #pragma unroll
    for (int i = 0; i < 4; ++i) {
        int node = m0 + ty * 4 + i;
        float s = (node < n_nodes) ? norm[node] : 0.f;
        unsigned short r[8];
        #pragma unroll
        for (int j = 0; j < 8; ++j) {
            float v = acc[i][j] + b1s[tx * 8 + j];
            v = v > 0.f ? v : 0.f;
            r[j] = f2bf(v * s);
        }
        unsigned short* o = Hs + (ty * 4 + i) * 138 + tx * 8;
        *(ushort4*)(o)     = make_ushort4(r[0], r[1], r[2], r[3]);
        *(ushort4*)(o + 4) = make_ushort4(r[4], r[5], r[6], r[7]);
    }
    __syncthreads();

    // ---- layer 2 ----
    float ac2[4][4];
    #pragma unroll
    for (int i = 0; i < 4; ++i)
        #pragma unroll
        for (int j = 0; j < 4; ++j) ac2[i][j] = 0.f;
    {
        const unsigned short* Hp = Hs + ty * 4 * 138;
        const unsigned short* Wp = W2b + tx * 4;
        for (int k = 0; k < 128; k += 4) {
            uint2 hr[4];
            #pragma unroll
            for (int i = 0; i < 4; ++i) hr[i] = *(const uint2*)(Hp + i * 138 + k);
            #pragma unroll
            for (int kk = 0; kk < 4; ++kk) {
                const uint2 wv = *(const uint2*)(Wp + (k + kk) * 64);
                float w0 = bf2f_lo(wv.x), w1 = bf2f_hi(wv.x);
                float w2 = bf2f_lo(wv.y), w3 = bf2f_hi(wv.y);
                #pragma unroll
                for (int i = 0; i < 4; ++i) {
                    unsigned int half = (kk < 2) ? hr[i].x : hr[i].y;
                    float a = (kk & 1) ? bf2f_hi(half) : bf2f_lo(half);
                    ac2[i][0] = fmaf(a, w0, ac2[i][0]);
                    ac2[i][1] = fmaf(a, w1, ac2[i][1]);
                    ac2[i][2] = fmaf(a, w2, ac2[i][2]);
                    ac2[i][3] = fmaf(a, w3, ac2[i][3]);
                }
            }
        }
    }
    #pragma unroll
    for (int i = 0; i < 4; ++i) {
        int node = m0 + ty * 4 + i;
        if (node < n_nodes) {
            ushort4 o;
            o.x = f2bf(ac2[i][0]); o.y = f2bf(ac2[i][1]);
            o.z = f2bf(ac2[i][2]); o.w = f2bf(ac2[i][3]);
            *(ushort4*)(y2b + (size_t)node * 64 + tx * 4) = o;
        }
    }
}

extern "C" void kernel_launch(void* const* d_in, const int* in_sizes, int n_in,
                              void* d_out, int out_size, void* d_ws, size_t ws_size,
                              hipStream_t stream) {
    const float* h   = (const float*)d_in[0];
    const int*   src = (const int*)d_in[1];
    const int*   dst = (const int*)d_in[2];
    const float* W1  = (const float*)d_in[3];
    const float* b1  = (const float*)d_in[4];
    const float* W2  = (const float*)d_in[5];
    const float* b2  = (const float*)d_in[6];
    float* out = (float*)d_out;

    const int n = in_sizes[0] / 64;
    const int E = in_sizes[1];
    const int nb = (n + 127) >> 7;

    char* p = (char*)d_ws;
    auto alloc = [&](size_t bytes) {
        void* r = (void*)p;
        p += (bytes + 255) & ~(size_t)255;
        return r;
    };
    float* norm_src      = (float*)alloc((size_t)n * 4);
    float* norm_dst      = (float*)alloc((size_t)n * 4);
    int2* node_rng       = (int2*)alloc((size_t)n * 8);
    int* cnt2            = (int*)alloc((size_t)2 * nb * 4);
    int* cnt_s = cnt2;
    int* cnt_d = cnt2 + nb;
    unsigned int* sd     = (unsigned int*)alloc((size_t)nb * CAP * 4);
    unsigned short* xb   = (unsigned short*)alloc((size_t)n * 64 * 2);
    unsigned short* agg1b= (unsigned short*)alloc((size_t)n * 64 * 2);
    unsigned short* y2b  = (unsigned short*)alloc((size_t)n * 64 * 2);
    unsigned short* srt  = (unsigned short*)alloc((size_t)nb * CAP * 2);
    unsigned char* ssb   = (unsigned char*)alloc((size_t)nb * CAP);

    hipMemsetAsync(cnt2, 0, 2 * (size_t)nb * sizeof(int), stream);

    place_direct<<<256, 256, 0, stream>>>(src, dst, cnt_s, cnt_d, ssb, sd, E, nb);
    prep<<<nb, 256, 0, stream>>>(h, ssb, cnt_s, sd, cnt_d, norm_src, xb,
                                 node_rng, srt, norm_dst, n);

    int gb = (n + 3) / 4;
    gather24<<<gb, 256, 0, stream>>>(xb, srt, node_rng, norm_dst, nullptr,
                                     (void*)agg1b, 1, n);

    int tb = (n + 63) / 64;
    gemm12<<<tb, 256, 0, stream>>>(agg1b, W1, b1, norm_src, W2, y2b, n);

    gather24<<<gb, 256, 0, stream>>>(y2b, srt, node_rng, norm_dst, b2,
                                     (void*)out, 0, n);
}

// Round 11
// 168.581 us; speedup vs baseline: 1.2936x; 1.2936x over previous
//
#include <hip/hip_runtime.h>

// F0=64, F1=128, F2=64. n<=65536, buckets of 128 nodes, slotted CSR with
// fixed bucket capacity CAP (no hist/scan passes).
// Pipeline: memset(cnt) -> place_direct -> prep(srcdeg+scale+bucketsort) ->
//           gather24(xb->agg1b bf16) -> gemm12_mfma (both layers, H in LDS)
//           -> gather24(y2b->out f32,+b2)

#define NBMAX 512
#define CAPLOG 12
#define CAP (1 << CAPLOG)

typedef __attribute__((ext_vector_type(8))) short bf16x8;
typedef __attribute__((ext_vector_type(4))) float f32x4;

__device__ inline unsigned short f2bf(float f) {
    unsigned int u = __float_as_uint(f);
    unsigned int r = (u + 0x7FFFu + ((u >> 16) & 1u)) >> 16;  // RNE
    return (unsigned short)r;
}
__device__ inline float bf2f_lo(unsigned int u) { return __uint_as_float(u << 16); }
__device__ inline float bf2f_hi(unsigned int u) { return __uint_as_float(u & 0xFFFF0000u); }
__device__ inline float bf2f(unsigned short h) {
    return __uint_as_float((unsigned int)h << 16);
}

// One pass over edges: per-block LDS hist -> one global reservation atomic per
// (block,bucket) -> LDS-cursor scatter into slotted bucket arrays.
// src entry: 1B local id. dst entry: (dst&127)<<25 | src.
__global__ __launch_bounds__(256) void place_direct(const int* __restrict__ src,
        const int* __restrict__ dst, int* __restrict__ cnt_s, int* __restrict__ cnt_d,
        unsigned char* __restrict__ ss, unsigned int* __restrict__ sd,
        int n_edges, int nb) {
    __shared__ int hs[NBMAX], hd[NBMAX], bs[NBMAX], bd[NBMAX];
    for (int i = threadIdx.x; i < nb; i += 256) { hs[i] = 0; hd[i] = 0; }
    __syncthreads();
    int chunk = (n_edges + gridDim.x - 1) / gridDim.x;
    int e0 = blockIdx.x * chunk;
    int e1 = e0 + chunk; if (e1 > n_edges) e1 = n_edges;
    for (int e = e0 + (int)threadIdx.x; e < e1; e += 256) {
        atomicAdd(&hs[src[e] >> 7], 1);
        atomicAdd(&hd[dst[e] >> 7], 1);
    }
    __syncthreads();
    for (int i = threadIdx.x; i < nb; i += 256) {
        int v = hs[i]; bs[i] = v ? atomicAdd(&cnt_s[i], v) : 0; hs[i] = 0;
        v = hd[i];     bd[i] = v ? atomicAdd(&cnt_d[i], v) : 0; hd[i] = 0;
    }
    __syncthreads();
    for (int e = e0 + (int)threadIdx.x; e < e1; e += 256) {
        int s = src[e], d = dst[e];
        int sb = s >> 7, db = d >> 7;
        int ps = bs[sb] + atomicAdd(&hs[sb], 1);
        ss[((size_t)sb << CAPLOG) + ps] = (unsigned char)(s & 127);
        int pd = bd[db] + atomicAdd(&hd[db], 1);
        sd[((size_t)db << CAPLOG) + pd] = ((unsigned int)(d & 127) << 25) | (unsigned int)s;
    }
}

// One block per bucket b:
//  phase 1 (src side): count ss local ids -> norm_src; xb = bf16(h * norm).
//  phase 2 (dst side): 128-bin count of sd -> scan -> node_rng + counting-sorted
//                      srt (u16 src ids) + norm_dst.
__global__ __launch_bounds__(256) void prep(const float* __restrict__ h,
        const unsigned char* __restrict__ ss, const int* __restrict__ cnt_s,
        const unsigned int* __restrict__ sd, const int* __restrict__ cnt_d,
        float* __restrict__ norm_src, unsigned short* __restrict__ xb,
        int2* __restrict__ node_rng, unsigned short* __restrict__ srt,
        float* __restrict__ norm_dst, int n) {
    __shared__ int cnt[128], cur[128];
    __shared__ float nrm[128];
    __shared__ int w0tot;
    const int b = blockIdx.x;
    const int tid = threadIdx.x;

    // ---- phase 1: src degree + scale/cast ----
    if (tid < 128) cnt[tid] = 0;
    __syncthreads();
    {
        int used = cnt_s[b];
        const unsigned char* p = ss + ((size_t)b << CAPLOG);
        for (int i = tid; i < used; i += 256) atomicAdd(&cnt[p[i]], 1);
    }
    __syncthreads();
    if (tid < 128) {
        int c = cnt[tid]; if (c < 1) c = 1;
        float s = 1.0f / sqrtf((float)c);
        nrm[tid] = s;
        int node = (b << 7) + tid;
        if (node < n) norm_src[node] = s;
    }
    __syncthreads();
    {
        int base = b << 7;
        for (int t = tid; t < 128 * 16; t += 256) {
            int r = t >> 4, c4 = (t & 15) << 2;
            int node = base + r;
            if (node < n) {
                float s = nrm[r];
                float4 v = *(const float4*)(h + (size_t)node * 64 + c4);
                ushort4 o;
                o.x = f2bf(v.x * s); o.y = f2bf(v.y * s);
                o.z = f2bf(v.z * s); o.w = f2bf(v.w * s);
                *(ushort4*)(xb + (size_t)node * 64 + c4) = o;
            }
        }
    }
    __syncthreads();

    // ---- phase 2: dst bucket counting sort ----
    if (tid < 128) cnt[tid] = 0;
    __syncthreads();
    int used = cnt_d[b];
    const unsigned int* p = sd + ((size_t)b << CAPLOG);
    for (int i = tid; i < used; i += 256) atomicAdd(&cnt[p[i] >> 25], 1);
    __syncthreads();
    int lane = tid & 63, wid = tid >> 6;
    int v = (tid < 128) ? cnt[tid] : 0;
    int incl = v;
    #pragma unroll
    for (int d = 1; d < 64; d <<= 1) {
        int t = __shfl_up(incl, d, 64);
        if (lane >= d) incl += t;
    }
    if (tid == 63) w0tot = incl;
    __syncthreads();
    if (tid < 128) {
        int excl = incl - v + (wid == 1 ? w0tot : 0);
        cur[tid] = excl;
        int node = (b << 7) + tid;
        if (node < n) {
            int base = b << CAPLOG;
            node_rng[node] = make_int2(base + excl, base + excl + v);
            int c = v; if (c < 1) c = 1;
            norm_dst[node] = 1.0f / sqrtf((float)c);
        }
    }
    __syncthreads();
    for (int i = tid; i < used; i += 256) {
        unsigned int e = p[i];
        int l = (int)(e >> 25);
        int pos = atomicAdd(&cur[l], 1);
        srt[((size_t)b << CAPLOG) + pos] = (unsigned short)(e & 0xFFFFu);
    }
}

// One wave per dst node. 8 lanes x bf16x8 (16B dwordx4) cover the 64-wide row;
// 8 lane-groups x unroll 3 -> 24 edges in flight per round.
// f32 accumulate, 3-level shfl_xor reduce; writes bf16 row (mode 1) or f32
// row +bias (mode 0).
__global__ __launch_bounds__(256) void gather24(const unsigned short* __restrict__ xb,
        const unsigned short* __restrict__ srt, const int2* __restrict__ node_rng,
        const float* __restrict__ nrm, const float* __restrict__ bias,
        void* __restrict__ outp, int write_bf, int n_nodes) {
    int node = blockIdx.x * 4 + (threadIdx.x >> 6);
    if (node >= n_nodes) return;
    int lane = threadIdx.x & 63;
    int g  = lane >> 3;         // edge slot 0..7
    int c8 = (lane & 7) * 8;    // column base
    int2 rng = node_rng[node];
    int a0 = rng.x, a1 = rng.y;
    float acc[8];
    #pragma unroll
    for (int j = 0; j < 8; ++j) acc[j] = 0.f;
    for (int base = a0; base < a1; base += 24) {
        #pragma unroll
        for (int u = 0; u < 3; ++u) {
            int ei = base + u * 8 + g;
            int idx = ei < a1 ? ei : a1 - 1;
            float msk = ei < a1 ? 1.0f : 0.0f;
            int s = srt[idx];
            const uint4 v = *(const uint4*)(xb + (size_t)s * 64 + c8);
            acc[0] = fmaf(bf2f_lo(v.x), msk, acc[0]);
            acc[1] = fmaf(bf2f_hi(v.x), msk, acc[1]);
            acc[2] = fmaf(bf2f_lo(v.y), msk, acc[2]);
            acc[3] = fmaf(bf2f_hi(v.y), msk, acc[3]);
            acc[4] = fmaf(bf2f_lo(v.z), msk, acc[4]);
            acc[5] = fmaf(bf2f_hi(v.z), msk, acc[5]);
            acc[6] = fmaf(bf2f_lo(v.w), msk, acc[6]);
            acc[7] = fmaf(bf2f_hi(v.w), msk, acc[7]);
        }
    }
    #pragma unroll
    for (int off = 8; off < 64; off <<= 1) {
        #pragma unroll
        for (int j = 0; j < 8; ++j) acc[j] += __shfl_xor(acc[j], off, 64);
    }
    if (g == 0) {
        float s = nrm[node];
        float r[8];
        #pragma unroll
        for (int j = 0; j < 8; ++j) r[j] = acc[j] * s;
        if (write_bf) {
            unsigned short rb[8];
            #pragma unroll
            for (int j = 0; j < 8; ++j) rb[j] = f2bf(r[j]);
            unsigned short* o = (unsigned short*)outp + (size_t)node * 64 + c8;
            *(ushort4*)(o)     = make_ushort4(rb[0], rb[1], rb[2], rb[3]);
            *(ushort4*)(o + 4) = make_ushort4(rb[4], rb[5], rb[6], rb[7]);
        } else {
            if (bias) {
                #pragma unroll
                for (int j = 0; j < 8; ++j) r[j] += bias[c8 + j];
            }
            float* o = (float*)outp + (size_t)node * 64 + c8;
            *(float4*)(o)     = make_float4(r[0], r[1], r[2], r[3]);
            *(float4*)(o + 4) = make_float4(r[4], r[5], r[6], r[7]);
        }
    }
}

// MFMA fused both layers per 64-node tile. 4 waves, wave w owns nodes
// m0+w*16..+15.  Layouts (verified per guide m89/m91/m120):
//   A-frag  lane l: A[m = l&15][k = (l>>4)*8 + j]     (bf16x8, 16B/lane)
//   B-frag  lane l: B[k = (l>>4)*8 + j][n = l&15]
//   C/D     lane l reg r: D[m = (l>>4)*4 + r][n = l&15]
// W1t/W2t staged transposed in LDS so B-frags are contiguous-k b128 reads.
// H tile (layer-1 out) goes through LDS (C-layout -> A-layout transform).
__global__ __launch_bounds__(256) void gemm12(const unsigned short* __restrict__ Ab,
        const float* __restrict__ W1, const float* __restrict__ b1,
        const float* __restrict__ norm, const float* __restrict__ W2,
        unsigned short* __restrict__ y2b, int n) {
    __shared__ unsigned short W1t[128 * 72];   // [n][k] pad 72 (2-way, free)
    __shared__ unsigned short W2t[64 * 136];   // [n][k] pad 136
    __shared__ unsigned short Hs[64 * 136];    // [m][k] pad 136
    __shared__ float b1s[128];
    const int tid = threadIdx.x;

    for (int i = tid; i < 8192; i += 256) {          // W1[64][128] -> W1t[n][k]
        int k = i >> 7, nn = i & 127;
        W1t[nn * 72 + k] = f2bf(W1[i]);
    }
    for (int i = tid; i < 8192; i += 256) {          // W2[128][64] -> W2t[n][k]
        int k = i >> 6, nn = i & 63;
        W2t[nn * 136 + k] = f2bf(W2[i]);
    }
    if (tid < 128) b1s[tid] = b1[tid];
    __syncthreads();

    const int w  = tid >> 6;
    const int l  = tid & 63;
    const int ln = l & 15;
    const int q  = l >> 4;
    const int m0 = blockIdx.x * 64 + w * 16;

    // A-frags straight from global (dense 16B/lane)
    int arow = m0 + ln; if (arow > n - 1) arow = n - 1;
    const unsigned short* arp = Ab + (size_t)arow * 64 + q * 8;
    bf16x8 a0 = *(const bf16x8*)(arp);
    bf16x8 a1 = *(const bf16x8*)(arp + 32);

    // norm_src for this lane's 4 output rows
    float ns[4];
    #pragma unroll
    for (int r = 0; r < 4; ++r) {
        int node = m0 + q * 4 + r;
        ns[r] = norm[node < n ? node : n - 1];
    }

    // ---- layer 1: 8 col-tiles x (2 MFMA, K=64) ----
    #pragma unroll
    for (int c = 0; c < 8; ++c) {
        const unsigned short* bp = W1t + (c * 16 + ln) * 72 + q * 8;
        bf16x8 b0 = *(const bf16x8*)(bp);
        bf16x8 bk = *(const bf16x8*)(bp + 32);
        f32x4 acc = {0.f, 0.f, 0.f, 0.f};
        acc = __builtin_amdgcn_mfma_f32_16x16x32_bf16(a0, b0, acc, 0, 0, 0);
        acc = __builtin_amdgcn_mfma_f32_16x16x32_bf16(a1, bk, acc, 0, 0, 0);
        int col = c * 16 + ln;
        float bb = b1s[col];
        #pragma unroll
        for (int r = 0; r < 4; ++r) {
            float v = acc[r] + bb;
            v = v > 0.f ? v : 0.f;
            Hs[(w * 16 + q * 4 + r) * 136 + col] = f2bf(v * ns[r]);
        }
    }
    __syncthreads();

    // ---- layer 2: 4 col-tiles x (4 MFMA, K=128) ----
    const unsigned short* hp = Hs + (size_t)(w * 16 + ln) * 136 + q * 8;
    bf16x8 h0 = *(const bf16x8*)(hp);
    bf16x8 h1 = *(const bf16x8*)(hp + 32);
    bf16x8 h2 = *(const bf16x8*)(hp + 64);
    bf16x8 h3 = *(const bf16x8*)(hp + 96);
    #pragma unroll
    for (int c = 0; c < 4; ++c) {
        const unsigned short* bp = W2t + (c * 16 + ln) * 136 + q * 8;
        f32x4 acc = {0.f, 0.f, 0.f, 0.f};
        acc = __builtin_amdgcn_mfma_f32_16x16x32_bf16(h0, *(const bf16x8*)(bp),      acc, 0, 0, 0);
        acc = __builtin_amdgcn_mfma_f32_16x16x32_bf16(h1, *(const bf16x8*)(bp + 32), acc, 0, 0, 0);
        acc = __builtin_amdgcn_mfma_f32_16x16x32_bf16(h2, *(const bf16x8*)(bp + 64), acc, 0, 0, 0);
        acc = __builtin_amdgcn_mfma_f32_16x16x32_bf16(h3, *(const bf16x8*)(bp + 96), acc, 0, 0, 0);
        #pragma unroll
        for (int r = 0; r < 4; ++r) {
            int node = m0 + q * 4 + r;
            if (node < n)
                y2b[(size_t)node * 64 + c * 16 + ln] = f2bf(acc[r]);
        }
    }
}

extern "C" void kernel_launch(void* const* d_in, const int* in_sizes, int n_in,
                              void* d_out, int out_size, void* d_ws, size_t ws_size,
                              hipStream_t stream) {
    const float* h   = (const float*)d_in[0];
    const int*   src = (const int*)d_in[1];
    const int*   dst = (const int*)d_in[2];
    const float* W1  = (const float*)d_in[3];
    const float* b1  = (const float*)d_in[4];
    const float* W2  = (const float*)d_in[5];
    const float* b2  = (const float*)d_in[6];
    float* out = (float*)d_out;

    const int n = in_sizes[0] / 64;
    const int E = in_sizes[1];
    const int nb = (n + 127) >> 7;

    char* p = (char*)d_ws;
    auto alloc = [&](size_t bytes) {
        void* r = (void*)p;
        p += (bytes + 255) & ~(size_t)255;
        return r;
    };
    float* norm_src      = (float*)alloc((size_t)n * 4);
    float* norm_dst      = (float*)alloc((size_t)n * 4);
    int2* node_rng       = (int2*)alloc((size_t)n * 8);
    int* cnt2            = (int*)alloc((size_t)2 * nb * 4);
    int* cnt_s = cnt2;
    int* cnt_d = cnt2 + nb;
    unsigned int* sd     = (unsigned int*)alloc((size_t)nb * CAP * 4);
    unsigned short* xb   = (unsigned short*)alloc((size_t)n * 64 * 2);
    unsigned short* agg1b= (unsigned short*)alloc((size_t)n * 64 * 2);
    unsigned short* y2b  = (unsigned short*)alloc((size_t)n * 64 * 2);
    unsigned short* srt  = (unsigned short*)alloc((size_t)nb * CAP * 2);
    unsigned char* ssb   = (unsigned char*)alloc((size_t)nb * CAP);

    hipMemsetAsync(cnt2, 0, 2 * (size_t)nb * sizeof(int), stream);

    place_direct<<<256, 256, 0, stream>>>(src, dst, cnt_s, cnt_d, ssb, sd, E, nb);
    prep<<<nb, 256, 0, stream>>>(h, ssb, cnt_s, sd, cnt_d, norm_src, xb,
                                 node_rng, srt, norm_dst, n);

    int gb = (n + 3) / 4;
    gather24<<<gb, 256, 0, stream>>>(xb, srt, node_rng, norm_dst, nullptr,
                                     (void*)agg1b, 1, n);

    int tb = (n + 63) / 64;
    gemm12<<<tb, 256, 0, stream>>>(agg1b, W1, b1, norm_src, W2, y2b, n);

    gather24<<<gb, 256, 0, stream>>>(y2b, srt, node_rng, norm_dst, b2,
                                     (void*)out, 0, n);
}